// Round 2
// baseline (928.787 us; speedup 1.0000x reference)
//
#include <hip/hip_runtime.h>
#include <cstdio>

// Problem dims
#define BATCH 256
#define TSEQ  393      // pooled sequence length
#define CH    128      // conv out channels == LSTM input
#define FIN   3
#define TIN   800
#define KK    15
#define HID   150
#define G4    600      // 4*HID
#define NPAD  640      // padded gate dim (40 tiles of 16)
#define KPAD  160      // padded hidden dim (5 ksteps of 32)
#define NB    16       // batch tile per recurrence block

typedef __attribute__((ext_vector_type(8))) short s8v;
typedef __attribute__((ext_vector_type(4))) short s4v;
typedef __attribute__((ext_vector_type(4))) float f4v;
using u16 = unsigned short;

__device__ inline float bf2f(u16 u){
  unsigned int x = ((unsigned int)u) << 16; float f; __builtin_memcpy(&f,&x,4); return f;
}
__device__ inline u16 f2bf(float f){
  unsigned int x; __builtin_memcpy(&x,&f,4);
  unsigned int r = x + 0x7FFFu + ((x>>16)&1u);
  return (u16)(r>>16);
}
__device__ inline float hsig(float x){ return fminf(fmaxf(0.2f*x + 0.5f, 0.f), 1.f); }
__device__ inline float tanh_(float x){ return 1.f - 2.f/(__expf(2.f*x) + 1.f); }

// ---------------- weight prep (fp32 -> padded bf16) ----------------
__global__ void prep_wih(const float* __restrict__ wf, const float* __restrict__ wb,
                         u16* __restrict__ out){
  int i = blockIdx.x*256 + threadIdx.x;           // 2*NPAD*CH
  if (i >= 2*NPAD*CH) return;
  int d = i / (NPAD*CH); int r = (i / CH) % NPAD; int c = i % CH;
  const float* src = d ? wb : wf;
  float v = (r < G4) ? src[r*CH + c] : 0.f;
  out[i] = f2bf(v);
}
__global__ void prep_whh(const float* __restrict__ wf, const float* __restrict__ wb,
                         u16* __restrict__ out){
  int i = blockIdx.x*256 + threadIdx.x;           // 2*NPAD*KPAD
  if (i >= 2*NPAD*KPAD) return;
  int d = i / (NPAD*KPAD); int r = (i / KPAD) % NPAD; int k = i % KPAD;
  const float* src = d ? wb : wf;
  float v = (r < G4 && k < HID) ? src[r*HID + k] : 0.f;
  out[i] = f2bf(v);
}
__global__ void prep_bsum(const float* __restrict__ bihf, const float* __restrict__ bhhf,
                          const float* __restrict__ bihb, const float* __restrict__ bhhb,
                          float* __restrict__ out){
  int i = blockIdx.x*256 + threadIdx.x;           // 2*NPAD
  if (i >= 2*NPAD) return;
  int d = i / NPAD; int r = i % NPAD;
  float v = 0.f;
  if (r < G4) v = d ? (bihb[r] + bhhb[r]) : (bihf[r] + bhhf[r]);
  out[i] = v;
}

// ---------------- conv1d + relu + maxpool2 -> xseq bf16 [B][T][C] ----------------
__global__ void conv_pool(const float* __restrict__ x, const float* __restrict__ w,
                          const float* __restrict__ bias, u16* __restrict__ xseq){
  int gid = blockIdx.x*256 + threadIdx.x;
  if (gid >= BATCH*TSEQ*CH) return;
  int c = gid & (CH-1);
  int t = (gid >> 7) % TSEQ;
  int b = gid / (CH*TSEQ);
  const float* xb = x + (size_t)b*FIN*TIN;
  const float* wc = w + c*FIN*KK;
  float a0 = 0.f, a1 = 0.f;
  int p = 2*t;
  #pragma unroll
  for (int f = 0; f < FIN; ++f){
    float xv[KK+1];
    #pragma unroll
    for (int k = 0; k < KK+1; ++k) xv[k] = xb[f*TIN + p + k];
    #pragma unroll
    for (int k = 0; k < KK; ++k){
      a0 = fmaf(xv[k],   wc[f*KK+k], a0);
      a1 = fmaf(xv[k+1], wc[f*KK+k], a1);
    }
  }
  float v = fmaxf(fmaxf(a0, a1) + bias[c], 0.f);
  xseq[gid] = f2bf(v);
}

// ---------------- fused recurrence: gates = x_t @ W_ih^T + h @ W_hh^T + bias ----------------
// grid (16, 2): blockIdx.x = batch tile (16 rows), blockIdx.y = direction.
// 512 threads = 8 waves; wave wv owns n-tiles wv*5 .. wv*5+4 (16 gates each).
// W_ih + W_hh B-fragments live in registers for all 393 steps (~180 VGPRs).
__global__ __launch_bounds__(512) void recur(const u16* __restrict__ xseq,
                                             const u16* __restrict__ wih,
                                             const u16* __restrict__ whh,
                                             const float* __restrict__ bsum,
                                             float* __restrict__ pooled){
  __shared__ __align__(16) u16 h_lds[NB][168];    // bf16 h, k-padded (cols 150..167 stay 0)
  __shared__ __align__(16) u16 x_lds[NB][136];    // bf16 x_t tile (cols 128..135 unused)
  __shared__ float glds[NPAD][21];                // gate exchange, transposed [n][b], pad 21

  int tid = threadIdx.x, wv = tid >> 6, ln = tid & 63;
  int m = ln & 15, kg = ln >> 4;
  int bt = blockIdx.x, d = blockIdx.y;
  int b0 = bt*NB;

  for (int i = tid; i < NB*168; i += 512) ((u16*)h_lds)[i] = 0;

  // resident weight fragments
  s8v bhh[5][5], bih[5][4];
  float breg[5];
  #pragma unroll
  for (int i = 0; i < 5; ++i){
    int n = (wv*5 + i)*16 + m;
    #pragma unroll
    for (int ks = 0; ks < 5; ++ks)
      bhh[i][ks] = *(const s8v*)(whh + ((size_t)d*NPAD + n)*KPAD + ks*32 + kg*8);
    #pragma unroll
    for (int ks = 0; ks < 4; ++ks)
      bih[i][ks] = *(const s8v*)(wih + ((size_t)d*NPAD + n)*CH + ks*32 + kg*8);
    breg[i] = bsum[d*NPAD + n];
  }

  // gate-phase / staging ownership: row gb = tid>>5, 32 threads per row
  int gb = tid >> 5, gj = tid & 31;
  float c_reg[5]  = {0.f, 0.f, 0.f, 0.f, 0.f};
  float hm_reg[5] = {-1e30f, -1e30f, -1e30f, -1e30f, -1e30f};

  int c4 = gj*4;                                   // 4 u16 per thread per stage
  const u16* xrow = xseq + (size_t)(b0 + gb)*TSEQ*CH + c4;

  int tt0 = d ? (TSEQ-1) : 0;
  { s4v v = *(const s4v*)(xrow + (size_t)tt0*CH);
    *(s4v*)(&x_lds[gb][c4]) = v; }
  __syncthreads();

  int step = d ? -1 : 1;
  int tt = tt0;
  #pragma unroll 1
  for (int t = 0; t < TSEQ; ++t){
    int ttn = (t < TSEQ-1) ? (tt + step) : tt;
    s4v nxt = *(const s4v*)(xrow + (size_t)ttn*CH);   // prefetch next step's x tile

    // A fragments from LDS
    s8v ah[5], ax[4];
    #pragma unroll
    for (int ks = 0; ks < 5; ++ks) ah[ks] = *(const s8v*)(&h_lds[m][ks*32 + kg*8]);
    #pragma unroll
    for (int ks = 0; ks < 4; ++ks) ax[ks] = *(const s8v*)(&x_lds[m][ks*32 + kg*8]);

    // gates (f32 accum, bias preloaded into acc)
    #pragma unroll
    for (int i = 0; i < 5; ++i){
      f4v acc = {breg[i], breg[i], breg[i], breg[i]};
      #pragma unroll
      for (int ks = 0; ks < 4; ++ks)
        acc = __builtin_amdgcn_mfma_f32_16x16x32_bf16(ax[ks], bih[i][ks], acc, 0, 0, 0);
      #pragma unroll
      for (int ks = 0; ks < 5; ++ks)
        acc = __builtin_amdgcn_mfma_f32_16x16x32_bf16(ah[ks], bhh[i][ks], acc, 0, 0, 0);
      int n = (wv*5 + i)*16 + m;
      *(f4v*)(&glds[n][kg*4]) = acc;                // D: col=lane&15 -> n, rows kg*4+r -> b
    }
    asm volatile("s_waitcnt lgkmcnt(0)" ::: "memory");
    __builtin_amdgcn_s_barrier();
    __builtin_amdgcn_sched_barrier(0);

    // stage prefetched next-step x tile (readers are beyond the next barrier)
    *(s4v*)(&x_lds[gb][c4]) = nxt;

    // gate nonlinearities + state update (f32); c/hmax in registers
    #pragma unroll
    for (int r = 0; r < 5; ++r){
      int j = gj + 32*r;
      if (j < HID){
        float ig = glds[j      ][gb];
        float fg = glds[150 + j][gb];
        float gg = glds[300 + j][gb];
        float og = glds[450 + j][gb];
        float cn = hsig(fg)*c_reg[r] + hsig(ig)*tanh_(gg);
        float hn = hsig(og)*tanh_(cn);
        c_reg[r] = cn;
        h_lds[gb][j] = f2bf(hn);
        hm_reg[r] = fmaxf(hm_reg[r], hn);
      }
    }
    asm volatile("s_waitcnt lgkmcnt(0)" ::: "memory");
    __builtin_amdgcn_s_barrier();
    __builtin_amdgcn_sched_barrier(0);
    tt = ttn;
  }

  #pragma unroll
  for (int r = 0; r < 5; ++r){
    int j = gj + 32*r;
    if (j < HID) pooled[(size_t)(b0 + gb)*300 + d*HID + j] = hm_reg[r];
  }
}

// ---------------- final MLP + softmax ----------------
__global__ __launch_bounds__(64) void fc(const float* __restrict__ pooled,
                                         const float* __restrict__ w1, const float* __restrict__ b1,
                                         const float* __restrict__ w2, const float* __restrict__ b2,
                                         float* __restrict__ out){
  __shared__ float prow[300];
  __shared__ float z[50];
  __shared__ float lg[10];
  int b = blockIdx.x, tid = threadIdx.x;
  for (int i = tid; i < 300; i += 64) prow[i] = pooled[(size_t)b*300 + i];
  __syncthreads();
  if (tid < 50){
    float a = b1[tid];
    for (int k = 0; k < 300; ++k) a = fmaf(prow[k], w1[tid*300 + k], a);
    z[tid] = fmaxf(a, 0.f);
  }
  __syncthreads();
  if (tid < 10){
    float a = b2[tid];
    for (int k = 0; k < 50; ++k) a = fmaf(z[k], w2[tid*50 + k], a);
    lg[tid] = a;
  }
  __syncthreads();
  if (tid < 10){
    float mx = lg[0];
    #pragma unroll
    for (int k = 1; k < 10; ++k) mx = fmaxf(mx, lg[k]);
    float s = 0.f;
    #pragma unroll
    for (int k = 0; k < 10; ++k) s += __expf(lg[k] - mx);
    out[(size_t)b*10 + tid] = __expf(lg[tid] - mx) / s;
  }
}

extern "C" void kernel_launch(void* const* d_in, const int* in_sizes, int n_in,
                              void* d_out, int out_size, void* d_ws, size_t ws_size,
                              hipStream_t stream) {
  const float* x      = (const float*)d_in[0];
  const float* conv_w = (const float*)d_in[1];
  const float* conv_b = (const float*)d_in[2];
  const float* w_ih_f = (const float*)d_in[3];
  const float* w_hh_f = (const float*)d_in[4];
  const float* b_ih_f = (const float*)d_in[5];
  const float* b_hh_f = (const float*)d_in[6];
  const float* w_ih_b = (const float*)d_in[7];
  const float* w_hh_b = (const float*)d_in[8];
  const float* b_ih_b = (const float*)d_in[9];
  const float* b_hh_b = (const float*)d_in[10];
  const float* l1w = (const float*)d_in[11];
  const float* l1b = (const float*)d_in[12];
  const float* l2w = (const float*)d_in[13];
  const float* l2b = (const float*)d_in[14];
  float* out = (float*)d_out;

  char* ws = (char*)d_ws;
  size_t off = 0;
  auto alloc = [&](size_t bytes){ size_t o = off; off += (bytes + 255) & ~(size_t)255; return o; };
  size_t xseq_o = alloc((size_t)BATCH*TSEQ*CH*2);
  size_t wih_o  = alloc((size_t)2*NPAD*CH*2);
  size_t whh_o  = alloc((size_t)2*NPAD*KPAD*2);
  size_t bs_o   = alloc((size_t)2*NPAD*4);
  size_t pool_o = alloc((size_t)BATCH*300*4);
  if (off > ws_size){
    fprintf(stderr, "[cnnblstm] WS TOO SMALL: need %zu have %zu\n", off, ws_size);
    return;
  }
  u16*   xseq_p = (u16*)(ws + xseq_o);
  u16*   wih_p  = (u16*)(ws + wih_o);
  u16*   whh_p  = (u16*)(ws + whh_o);
  float* bs_p   = (float*)(ws + bs_o);
  float* pool_p = (float*)(ws + pool_o);

  prep_wih <<<(2*NPAD*CH + 255)/256, 256, 0, stream>>>(w_ih_f, w_ih_b, wih_p);
  prep_whh <<<(2*NPAD*KPAD + 255)/256, 256, 0, stream>>>(w_hh_f, w_hh_b, whh_p);
  prep_bsum<<<(2*NPAD + 255)/256, 256, 0, stream>>>(b_ih_f, b_hh_f, b_ih_b, b_hh_b, bs_p);
  conv_pool<<<(BATCH*TSEQ*CH)/256, 256, 0, stream>>>(x, conv_w, conv_b, xseq_p);
  recur    <<<dim3(BATCH/NB, 2), 512, 0, stream>>>(xseq_p, wih_p, whh_p, bs_p, pool_p);
  fc       <<<BATCH, 64, 0, stream>>>(pool_p, l1w, l1b, l2w, l2b, out);
}

// Round 4
// 726.556 us; speedup vs baseline: 1.2783x; 1.2783x over previous
//
#include <hip/hip_runtime.h>
#include <cstdio>

#define BATCH 256
#define TSEQ  393
#define CH    128
#define FIN   3
#define TIN   800
#define KK    15
#define HID   150
#define NPAD  640      // interleaved gate dim: n = 4*j + gate, j<160 (j>=150 pad)
#define KPAD  160      // padded hidden dim for W_hh
#define NB    16       // batch rows per recurrence block
#define PHASE 131      // slots per phase (3*131 = 393)
#define SLOTSTRIDE (16*10240)   // floats between consecutive slots

typedef _Float16 half_t;
typedef __attribute__((ext_vector_type(8))) _Float16 h8v;
typedef __attribute__((ext_vector_type(4))) float f4v;

__device__ inline float hsig(float x){ return fminf(fmaxf(fmaf(0.2f, x, 0.5f), 0.f), 1.f); }
__device__ inline float tanh_(float x){
  float e = __expf(2.f*x);
  return fmaf(-2.f, __builtin_amdgcn_rcpf(e + 1.f), 1.f);
}

#define DPPF(v, ctrl) __int_as_float(__builtin_amdgcn_mov_dpp(__float_as_int(v), ctrl, 0xF, 0xF, true))
#define XPOSE_PAIR(va, vb, om, CTRL) { float t_ = om ? va : vb; t_ = DPPF(t_, CTRL); va = om ? t_ : va; vb = om ? vb : t_; }

// ---------------- weight prep (fp32 -> f16, gate-interleaved rows) ----------------
// row map: n = 4*j + g (g in i,f,g,o order), valid when n<600 (j<150)
__global__ void prep_wih(const float* __restrict__ wf, const float* __restrict__ wb,
                         half_t* __restrict__ out){
  int i = blockIdx.x*256 + threadIdx.x;          // 2*640*128
  if (i >= 2*NPAD*CH) return;
  int c = i & 127; int n = (i >> 7) % NPAD; int d = i / (NPAD*CH);
  const float* src = d ? wb : wf;
  float v = 0.f;
  if (n < 600){ int j = n >> 2, g = n & 3; v = src[(g*HID + j)*CH + c]; }
  out[i] = (half_t)v;
}
// W_hh canonical columns (no permutation — plain ds_read_b128 A-frags)
__global__ void prep_whh(const float* __restrict__ wf, const float* __restrict__ wb,
                         half_t* __restrict__ out){
  int i = blockIdx.x*256 + threadIdx.x;          // 2*640*160
  if (i >= 2*NPAD*KPAD) return;
  int kc = i % KPAD; int n = (i / KPAD) % NPAD; int d = i / (NPAD*KPAD);
  const float* src = d ? wb : wf;
  float v = 0.f;
  if (n < 600 && kc < HID){ int j = n >> 2, g = n & 3; v = src[(g*HID + j)*HID + kc]; }
  out[i] = (half_t)v;
}
__global__ void prep_bsum(const float* __restrict__ bihf, const float* __restrict__ bhhf,
                          const float* __restrict__ bihb, const float* __restrict__ bhhb,
                          float* __restrict__ out){
  int i = blockIdx.x*256 + threadIdx.x;          // 2*640
  if (i >= 2*NPAD) return;
  int n = i % NPAD; int d = i / NPAD;
  float v = 0.f;
  if (n < 600){ int j = n >> 2, g = n & 3; int r = g*HID + j;
    v = d ? (bihb[r] + bhhb[r]) : (bihf[r] + bhhf[r]); }
  out[i] = v;
}

// ---------------- conv1d + relu + maxpool2 -> xseq f16 [B][T][C] ----------------
#define CTT 32
__global__ __launch_bounds__(256) void conv_pool(const float* __restrict__ x,
                                                 const float* __restrict__ w,
                                                 const float* __restrict__ bias,
                                                 half_t* __restrict__ xseq){
  __shared__ float wl[CH*FIN*KK];
  __shared__ float xl[FIN][2*CTT + 14];
  int tid = threadIdx.x;
  int b = blockIdx.x, t0 = blockIdx.y*CTT;
  for (int i = tid; i < CH*FIN*KK; i += 256) wl[i] = w[i];
  int p0 = 2*t0;
  for (int i = tid; i < FIN*(2*CTT+14); i += 256){
    int f = i/(2*CTT+14), q = i%(2*CTT+14);
    int p = p0 + q;
    xl[f][q] = (p < TIN) ? x[((size_t)b*FIN + f)*TIN + p] : 0.f;
  }
  __syncthreads();
  int c = tid & 127, th = tid >> 7;
  float a0[16], a1[16];
  #pragma unroll
  for (int i=0;i<16;++i){ a0[i]=0.f; a1[i]=0.f; }
  #pragma unroll
  for (int f=0; f<FIN; ++f){
    float xv[46];
    #pragma unroll
    for (int q=0;q<46;++q) xv[q] = xl[f][th*32 + q];
    #pragma unroll
    for (int k=0;k<KK;++k){
      float ws = wl[c*FIN*KK + f*KK + k];
      #pragma unroll
      for (int i=0;i<16;++i){
        a0[i] = fmaf(xv[2*i+k],   ws, a0[i]);
        a1[i] = fmaf(xv[2*i+k+1], ws, a1[i]);
      }
    }
  }
  float bc = bias[c];
  #pragma unroll
  for (int i=0;i<16;++i){
    int t = t0 + th*16 + i;
    if (t < TSEQ){
      float v = fmaxf(fmaxf(a0[i], a1[i]) + bc, 0.f);
      xseq[((size_t)b*TSEQ + t)*CH + c] = (half_t)v;
    }
  }
}

// ---------------- x-projection: pre[d][slot][bt16][n640][b16] f32 ----------------
__global__ __launch_bounds__(512) void proj(const half_t* __restrict__ xseq,
                                            const half_t* __restrict__ wih,
                                            const float* __restrict__ bsum,
                                            float* __restrict__ pre,
                                            int off){
  int bt4 = blockIdx.x;       // 4 blocks of 64 batch rows
  int s   = blockIdx.y;
  int d   = blockIdx.z;
  int sg  = s + off;
  int t   = d ? (TSEQ-1 - sg) : sg;
  int tid = threadIdx.x, wv = tid >> 6, ln = tid & 63;
  int m = ln & 15, kg = ln >> 4;

  h8v bfr[5][4]; float bs[5];
  #pragma unroll
  for (int i = 0; i < 5; ++i){
    int n = (wv*5 + i)*16 + m;
    #pragma unroll
    for (int ks = 0; ks < 4; ++ks)
      bfr[i][ks] = *(const h8v*)(wih + ((size_t)d*NPAD + n)*CH + ks*32 + kg*8);
    bs[i] = bsum[d*NPAD + n];
  }
  #pragma unroll
  for (int ms = 0; ms < 4; ++ms){
    int b = bt4*64 + ms*16 + m;
    h8v ax[4];
    #pragma unroll
    for (int ks = 0; ks < 4; ++ks)
      ax[ks] = *(const h8v*)(xseq + ((size_t)b*TSEQ + t)*CH + ks*32 + kg*8);
    #pragma unroll
    for (int i = 0; i < 5; ++i){
      f4v acc = {bs[i], bs[i], bs[i], bs[i]};
      #pragma unroll
      for (int ks = 0; ks < 4; ++ks)
        acc = __builtin_amdgcn_mfma_f32_16x16x32_f16(ax[ks], bfr[i][ks], acc, 0, 0, 0);
      int n = (wv*5 + i)*16 + m;
      *(f4v*)(pre + (((size_t)d*PHASE + s)*16 + (bt4*4 + ms))*10240 + n*16 + kg*4) = acc;
    }
  }
}

// ---------------- recurrence ----------------
// h_lds[2][16][168] f16 b-major; A-frags via plain ds_read_b128;
// gates exchanged in-register via quad DPP transpose; one barrier per step.
__global__ __launch_bounds__(512, 2) void recur(const float* __restrict__ pre,
                                                const half_t* __restrict__ whh,
                                                float* __restrict__ pooled,
                                                float* __restrict__ stateC,
                                                half_t* __restrict__ stateH,
                                                int first, int last){
  __shared__ __align__(16) half_t hbuf[2*NB*168];   // [2][16][168]

  int tid = threadIdx.x, wv = tid >> 6, ln = tid & 63;
  int m = ln & 15, kg = ln >> 4;
  int bt = blockIdx.x, d = blockIdx.y;
  int b0 = bt*NB;
  int blk = d*16 + bt;
  bool o1 = (ln & 1), o2 = (ln & 2);

  // resident W_hh fragments (5 n-tiles x 5 k-steps)
  h8v bhh[5][5];
  #pragma unroll
  for (int i = 0; i < 5; ++i){
    int n = (wv*5 + i)*16 + m;
    #pragma unroll
    for (int ks = 0; ks < 5; ++ks)
      bhh[i][ks] = *(const h8v*)(whh + ((size_t)d*NPAD + n)*KPAD + ks*32 + kg*8);
  }

  // per-lane cell/batch identity for gate phase
  int jc[5], bc_;
  bc_ = kg*4 + (m&3);
  #pragma unroll
  for (int T = 0; T < 5; ++T) jc[T] = 20*wv + 4*T + (m>>2);

  float c_reg[5], hm_reg[5];
  if (first){
    for (int i = tid; i < NB*168; i += 512) hbuf[i] = (half_t)0.f;
    for (int i = tid; i < NB*168; i += 512) hbuf[NB*168 + i] = (half_t)0.f;
    #pragma unroll
    for (int T = 0; T < 5; ++T){ c_reg[T] = 0.f; hm_reg[T] = -1e30f; }
  } else {
    for (int i = tid; i < NB*168; i += 512) hbuf[i] = stateH[(size_t)blk*NB*168 + i];
    for (int i = tid; i < NB*168; i += 512) hbuf[NB*168 + i] = (half_t)0.f;
    const float* sc = stateC + ((size_t)blk*512 + tid)*10;
    #pragma unroll
    for (int T = 0; T < 5; ++T){ c_reg[T] = sc[T]; hm_reg[T] = sc[5+T]; }
  }
  __syncthreads();

  const float* psrc = pre + ((size_t)d*PHASE*16 + bt)*10240;
  int pofl = wv*1280 + m*16 + kg*4;

  f4v curp[5];
  #pragma unroll
  for (int T = 0; T < 5; ++T) curp[T] = *(const f4v*)(psrc + pofl + T*256);

  int p = 0;
  #pragma unroll 1
  for (int s = 0; s < PHASE; ++s){
    const float* nsrc = psrc + ((s+1 < PHASE) ? SLOTSTRIDE : 0);
    f4v nxt[5];
    #pragma unroll
    for (int T = 0; T < 5; ++T) nxt[T] = *(const f4v*)(nsrc + pofl + T*256);

    // A fragments from h buffer p (b-major rows)
    const half_t* hrd = hbuf + p*NB*168 + m*168;
    h8v ah[5];
    #pragma unroll
    for (int ks = 0; ks < 5; ++ks) ah[ks] = *(const h8v*)(hrd + ks*32 + kg*8);

    f4v acc[5];
    #pragma unroll
    for (int T = 0; T < 5; ++T){
      f4v a = {0.f, 0.f, 0.f, 0.f};
      #pragma unroll
      for (int ks = 0; ks < 5; ++ks)
        a = __builtin_amdgcn_mfma_f32_16x16x32_f16(ah[ks], bhh[T][ks], a, 0, 0, 0);
      acc[T] = a;
    }

    half_t* hwr = hbuf + (p^1)*NB*168 + bc_*168;
    #pragma unroll
    for (int T = 0; T < 5; ++T){
      float v0 = acc[T][0] + curp[T][0];
      float v1 = acc[T][1] + curp[T][1];
      float v2 = acc[T][2] + curp[T][2];
      float v3 = acc[T][3] + curp[T][3];
      // quad 4x4 transpose: lane ends with (i,f,g,o) of its own cell
      XPOSE_PAIR(v0, v1, o1, 0xB1);
      XPOSE_PAIR(v2, v3, o1, 0xB1);
      XPOSE_PAIR(v0, v2, o2, 0x4E);
      XPOSE_PAIR(v1, v3, o2, 0x4E);
      float cn = hsig(v1)*c_reg[T] + hsig(v0)*tanh_(v2);
      float hn = hsig(v3)*tanh_(cn);
      c_reg[T] = cn;
      hm_reg[T] = fmaxf(hm_reg[T], hn);
      hwr[jc[T]] = (half_t)hn;
    }

    #pragma unroll
    for (int T = 0; T < 5; ++T) curp[T] = nxt[T];

    __syncthreads();
    p ^= 1;
    psrc += SLOTSTRIDE;
  }

  if (!last){
    for (int i = tid; i < NB*168; i += 512) stateH[(size_t)blk*NB*168 + i] = hbuf[p*NB*168 + i];
    float* sc = stateC + ((size_t)blk*512 + tid)*10;
    #pragma unroll
    for (int T = 0; T < 5; ++T){ sc[T] = c_reg[T]; sc[5+T] = hm_reg[T]; }
  } else {
    #pragma unroll
    for (int T = 0; T < 5; ++T){
      if (jc[T] < HID) pooled[(size_t)(b0 + bc_)*300 + d*HID + jc[T]] = hm_reg[T];
    }
  }
}

// ---------------- final MLP + softmax ----------------
__global__ __launch_bounds__(256) void fc(const float* __restrict__ pooled,
                                          const float* __restrict__ w1, const float* __restrict__ b1,
                                          const float* __restrict__ w2, const float* __restrict__ b2,
                                          float* __restrict__ out){
  __shared__ float prow[300];
  __shared__ float ps[64][5];
  __shared__ float z[52];
  __shared__ float lg[12];
  int b = blockIdx.x, tid = threadIdx.x;
  for (int i = tid; i < 300; i += 256) prow[i] = pooled[(size_t)b*300 + i];
  __syncthreads();
  int j = tid & 63, seg = tid >> 6;
  float a = 0.f;
  if (j < 50){
    const float* wr = w1 + (size_t)j*300 + seg*75;
    const float* pr = prow + seg*75;
    #pragma unroll 5
    for (int k = 0; k < 75; ++k) a = fmaf(pr[k], wr[k], a);
  }
  ps[j][seg] = a;
  __syncthreads();
  if (tid < 50) z[tid] = fmaxf(ps[tid][0]+ps[tid][1]+ps[tid][2]+ps[tid][3] + b1[tid], 0.f);
  __syncthreads();
  if (tid < 10){
    float a2 = b2[tid];
    for (int k = 0; k < 50; ++k) a2 = fmaf(z[k], w2[tid*50 + k], a2);
    lg[tid] = a2;
  }
  __syncthreads();
  if (tid < 10){
    float mx = lg[0];
    #pragma unroll
    for (int k = 1; k < 10; ++k) mx = fmaxf(mx, lg[k]);
    float ssum = 0.f;
    #pragma unroll
    for (int k = 0; k < 10; ++k) ssum += __expf(lg[k] - mx);
    out[(size_t)b*10 + tid] = __expf(lg[tid] - mx) / ssum;
  }
}

extern "C" void kernel_launch(void* const* d_in, const int* in_sizes, int n_in,
                              void* d_out, int out_size, void* d_ws, size_t ws_size,
                              hipStream_t stream) {
  const float* x      = (const float*)d_in[0];
  const float* conv_w = (const float*)d_in[1];
  const float* conv_b = (const float*)d_in[2];
  const float* w_ih_f = (const float*)d_in[3];
  const float* w_hh_f = (const float*)d_in[4];
  const float* b_ih_f = (const float*)d_in[5];
  const float* b_hh_f = (const float*)d_in[6];
  const float* w_ih_b = (const float*)d_in[7];
  const float* w_hh_b = (const float*)d_in[8];
  const float* b_ih_b = (const float*)d_in[9];
  const float* b_hh_b = (const float*)d_in[10];
  const float* l1w = (const float*)d_in[11];
  const float* l1b = (const float*)d_in[12];
  const float* l2w = (const float*)d_in[13];
  const float* l2b = (const float*)d_in[14];
  float* out = (float*)d_out;

  char* ws = (char*)d_ws;
  size_t off = 0;
  auto alloc = [&](size_t bytes){ size_t o = off; off += (bytes + 255) & ~(size_t)255; return o; };
  size_t xseq_o = alloc((size_t)BATCH*TSEQ*CH*2);
  size_t pre_o  = alloc((size_t)2*PHASE*16*10240*4);
  size_t wih_o  = alloc((size_t)2*NPAD*CH*2);
  size_t whh_o  = alloc((size_t)2*NPAD*KPAD*2);
  size_t bs_o   = alloc((size_t)2*NPAD*4);
  size_t pool_o = alloc((size_t)BATCH*300*4);
  size_t stc_o  = alloc((size_t)32*512*10*4);
  size_t sth_o  = alloc((size_t)32*NB*168*2);
  if (off > ws_size){
    fprintf(stderr, "[cnnblstm] WS TOO SMALL: need %zu have %zu\n", off, ws_size);
    return;
  }
  half_t* xseq_p = (half_t*)(ws + xseq_o);
  float*  pre_p  = (float*)(ws + pre_o);
  half_t* wih_p  = (half_t*)(ws + wih_o);
  half_t* whh_p  = (half_t*)(ws + whh_o);
  float*  bs_p   = (float*)(ws + bs_o);
  float*  pool_p = (float*)(ws + pool_o);
  float*  stc_p  = (float*)(ws + stc_o);
  half_t* sth_p  = (half_t*)(ws + sth_o);

  prep_wih <<<(2*NPAD*CH + 255)/256, 256, 0, stream>>>(w_ih_f, w_ih_b, wih_p);
  prep_whh <<<(2*NPAD*KPAD + 255)/256, 256, 0, stream>>>(w_hh_f, w_hh_b, whh_p);
  prep_bsum<<<(2*NPAD + 255)/256, 256, 0, stream>>>(b_ih_f, b_hh_f, b_ih_b, b_hh_b, bs_p);
  conv_pool<<<dim3(BATCH, (TSEQ + CTT - 1)/CTT), 256, 0, stream>>>(x, conv_w, conv_b, xseq_p);

  for (int q = 0; q < 3; ++q){
    proj <<<dim3(4, PHASE, 2), 512, 0, stream>>>(xseq_p, wih_p, bs_p, pre_p, q*PHASE);
    recur<<<dim3(16, 2), 512, 0, stream>>>(pre_p, whh_p, pool_p, stc_p, sth_p, q==0, q==2);
  }

  fc<<<BATCH, 256, 0, stream>>>(pool_p, l1w, l1b, l2w, l2b, out);
}

// Round 5
// 666.724 us; speedup vs baseline: 1.3931x; 1.0897x over previous
//
#include <hip/hip_runtime.h>
#include <cstdio>

#define BATCH 256
#define TSEQ  393
#define CH    128
#define FIN   3
#define TIN   800
#define KK    15
#define HID   150
#define NPAD  640      // interleaved gate dim: n = 4*j + gate, j<160 (j>=150 pad)
#define KPAD  160      // padded hidden dim for W_hh
#define NB    16       // batch rows per recurrence block
#define HALF_A 197
#define HALF_B 196
#define SLOTSTRIDE (16*10240)   // halves between consecutive slots

typedef _Float16 half_t;
typedef __attribute__((ext_vector_type(8))) _Float16 h8v;
typedef __attribute__((ext_vector_type(4))) _Float16 h4v;
typedef __attribute__((ext_vector_type(4))) float f4v;

__device__ inline float hsig(float x){ return fminf(fmaxf(fmaf(0.2f, x, 0.5f), 0.f), 1.f); }
__device__ inline float tanh_(float x){
  float e = __expf(2.f*x);
  return fmaf(-2.f, __builtin_amdgcn_rcpf(e + 1.f), 1.f);
}

#define DPPF(v, ctrl) __int_as_float(__builtin_amdgcn_mov_dpp(__float_as_int(v), ctrl, 0xF, 0xF, true))
#define XPOSE_PAIR(va, vb, om, CTRL) { float t_ = om ? va : vb; t_ = DPPF(t_, CTRL); va = om ? t_ : va; vb = om ? vb : t_; }

// ---------------- weight prep (fp32 -> f16, gate-interleaved rows) ----------------
// row map: n = 4*j + g (g in i,f,g,o order), valid when n<600 (j<150)
__global__ void prep_wih(const float* __restrict__ wf, const float* __restrict__ wb,
                         half_t* __restrict__ out){
  int i = blockIdx.x*256 + threadIdx.x;          // 2*640*128
  if (i >= 2*NPAD*CH) return;
  int c = i & 127; int n = (i >> 7) % NPAD; int d = i / (NPAD*CH);
  const float* src = d ? wb : wf;
  float v = 0.f;
  if (n < 600){ int j = n >> 2, g = n & 3; v = src[(g*HID + j)*CH + c]; }
  out[i] = (half_t)v;
}
// W_hh canonical columns (plain ds_read_b128 A-frags)
__global__ void prep_whh(const float* __restrict__ wf, const float* __restrict__ wb,
                         half_t* __restrict__ out){
  int i = blockIdx.x*256 + threadIdx.x;          // 2*640*160
  if (i >= 2*NPAD*KPAD) return;
  int kc = i % KPAD; int n = (i / KPAD) % NPAD; int d = i / (NPAD*KPAD);
  const float* src = d ? wb : wf;
  float v = 0.f;
  if (n < 600 && kc < HID){ int j = n >> 2, g = n & 3; v = src[(g*HID + j)*HID + kc]; }
  out[i] = (half_t)v;
}
__global__ void prep_bsum(const float* __restrict__ bihf, const float* __restrict__ bhhf,
                          const float* __restrict__ bihb, const float* __restrict__ bhhb,
                          float* __restrict__ out){
  int i = blockIdx.x*256 + threadIdx.x;          // 2*640
  if (i >= 2*NPAD) return;
  int n = i % NPAD; int d = i / NPAD;
  float v = 0.f;
  if (n < 600){ int j = n >> 2, g = n & 3; int r = g*HID + j;
    v = d ? (bihb[r] + bhhb[r]) : (bihf[r] + bhhf[r]); }
  out[i] = v;
}

// ---------------- conv1d + relu + maxpool2 -> xseq f16 [B][T][C] ----------------
#define CTT 32
__global__ __launch_bounds__(256) void conv_pool(const float* __restrict__ x,
                                                 const float* __restrict__ w,
                                                 const float* __restrict__ bias,
                                                 half_t* __restrict__ xseq){
  __shared__ float wl[CH*FIN*KK];
  __shared__ float xl[FIN][2*CTT + 14];
  int tid = threadIdx.x;
  int b = blockIdx.x, t0 = blockIdx.y*CTT;
  for (int i = tid; i < CH*FIN*KK; i += 256) wl[i] = w[i];
  int p0 = 2*t0;
  for (int i = tid; i < FIN*(2*CTT+14); i += 256){
    int f = i/(2*CTT+14), q = i%(2*CTT+14);
    int p = p0 + q;
    xl[f][q] = (p < TIN) ? x[((size_t)b*FIN + f)*TIN + p] : 0.f;
  }
  __syncthreads();
  int c = tid & 127, th = tid >> 7;
  float a0[16], a1[16];
  #pragma unroll
  for (int i=0;i<16;++i){ a0[i]=0.f; a1[i]=0.f; }
  #pragma unroll
  for (int f=0; f<FIN; ++f){
    float xv[46];
    #pragma unroll
    for (int q=0;q<46;++q) xv[q] = xl[f][th*32 + q];
    #pragma unroll
    for (int k=0;k<KK;++k){
      float ws = wl[c*FIN*KK + f*KK + k];
      #pragma unroll
      for (int i=0;i<16;++i){
        a0[i] = fmaf(xv[2*i+k],   ws, a0[i]);
        a1[i] = fmaf(xv[2*i+k+1], ws, a1[i]);
      }
    }
  }
  float bc = bias[c];
  #pragma unroll
  for (int i=0;i<16;++i){
    int t = t0 + th*16 + i;
    if (t < TSEQ){
      float v = fmaxf(fmaxf(a0[i], a1[i]) + bc, 0.f);
      xseq[((size_t)b*TSEQ + t)*CH + c] = (half_t)v;
    }
  }
}

// ---------------- x-projection: pre[d][slot][bt16][n640][b16] f16 ----------------
__global__ __launch_bounds__(512) void proj(const half_t* __restrict__ xseq,
                                            const half_t* __restrict__ wih,
                                            const float* __restrict__ bsum,
                                            half_t* __restrict__ pre,
                                            int off){
  int bt4 = blockIdx.x;       // 4 blocks of 64 batch rows
  int s   = blockIdx.y;
  int d   = blockIdx.z;
  int sg  = s + off;
  int t   = d ? (TSEQ-1 - sg) : sg;
  int tid = threadIdx.x, wv = tid >> 6, ln = tid & 63;
  int m = ln & 15, kg = ln >> 4;

  h8v bfr[5][4]; float bs[5];
  #pragma unroll
  for (int i = 0; i < 5; ++i){
    int n = (wv*5 + i)*16 + m;
    #pragma unroll
    for (int ks = 0; ks < 4; ++ks)
      bfr[i][ks] = *(const h8v*)(wih + ((size_t)d*NPAD + n)*CH + ks*32 + kg*8);
    bs[i] = bsum[d*NPAD + n];
  }
  #pragma unroll
  for (int ms = 0; ms < 4; ++ms){
    int b = bt4*64 + ms*16 + m;
    h8v ax[4];
    #pragma unroll
    for (int ks = 0; ks < 4; ++ks)
      ax[ks] = *(const h8v*)(xseq + ((size_t)b*TSEQ + t)*CH + ks*32 + kg*8);
    #pragma unroll
    for (int i = 0; i < 5; ++i){
      f4v acc = {bs[i], bs[i], bs[i], bs[i]};
      #pragma unroll
      for (int ks = 0; ks < 4; ++ks)
        acc = __builtin_amdgcn_mfma_f32_16x16x32_f16(ax[ks], bfr[i][ks], acc, 0, 0, 0);
      int n = (wv*5 + i)*16 + m;
      h4v hv = {(half_t)acc[0], (half_t)acc[1], (half_t)acc[2], (half_t)acc[3]};
      *(h4v*)(pre + (((size_t)d*HALF_A + s)*16 + (bt4*4 + ms))*10240 + n*16 + kg*4) = hv;
    }
  }
}

// ---------------- recurrence ----------------
// h_lds[2][16][168] f16 b-major; A-frags via plain ds_read_b128;
// gates exchanged in-register via quad DPP transpose; one lgkm-only barrier per step.
__global__ __launch_bounds__(512, 2) void recur(const half_t* __restrict__ pre,
                                                const half_t* __restrict__ whh,
                                                float* __restrict__ pooled,
                                                float* __restrict__ stateC,
                                                half_t* __restrict__ stateH,
                                                int first, int last, int nsteps){
  __shared__ __align__(16) half_t hbuf[2*NB*168];   // [2][16][168]

  int tid = threadIdx.x, wv = tid >> 6, ln = tid & 63;
  int m = ln & 15, kg = ln >> 4;
  int bt = blockIdx.x, d = blockIdx.y;
  int b0 = bt*NB;
  int blk = d*16 + bt;
  bool o1 = (ln & 1), o2 = (ln & 2);

  // resident W_hh fragments (5 n-tiles x 5 k-steps) — PINNED in VGPRs:
  // the "+v" value-barrier makes each fragment opaque so the compiler cannot
  // rematerialize the load inside the loop (R4: VGPR_Count=88 proved it did,
  // costing 200KB/block/step of L1 traffic = the whole 3200cy/step).
  h8v bhh[5][5];
  #pragma unroll
  for (int i = 0; i < 5; ++i){
    int n = (wv*5 + i)*16 + m;
    #pragma unroll
    for (int ks = 0; ks < 5; ++ks)
      bhh[i][ks] = *(const h8v*)(whh + ((size_t)d*NPAD + n)*KPAD + ks*32 + kg*8);
  }
  #pragma unroll
  for (int i = 0; i < 5; ++i)
    #pragma unroll
    for (int ks = 0; ks < 5; ++ks)
      asm volatile("" : "+v"(bhh[i][ks]));

  // per-lane cell/batch identity for gate phase
  int jc[5], bc_;
  bc_ = kg*4 + (m&3);
  #pragma unroll
  for (int T = 0; T < 5; ++T) jc[T] = 20*wv + 4*T + (m>>2);

  float c_reg[5], hm_reg[5];
  if (first){
    for (int i = tid; i < NB*168; i += 512) hbuf[i] = (half_t)0.f;
    for (int i = tid; i < NB*168; i += 512) hbuf[NB*168 + i] = (half_t)0.f;
    #pragma unroll
    for (int T = 0; T < 5; ++T){ c_reg[T] = 0.f; hm_reg[T] = -1e30f; }
  } else {
    for (int i = tid; i < NB*168; i += 512) hbuf[i] = stateH[(size_t)blk*NB*168 + i];
    for (int i = tid; i < NB*168; i += 512) hbuf[NB*168 + i] = (half_t)0.f;
    const float* sc = stateC + ((size_t)blk*512 + tid)*10;
    #pragma unroll
    for (int T = 0; T < 5; ++T){ c_reg[T] = sc[T]; hm_reg[T] = sc[5+T]; }
  }
  __syncthreads();

  const half_t* psrc = pre + ((size_t)d*HALF_A*16 + bt)*10240;
  int pofl = wv*1280 + m*16 + kg*4;

  h4v curp[5];
  #pragma unroll
  for (int T = 0; T < 5; ++T) curp[T] = *(const h4v*)(psrc + pofl + T*256);

  int p = 0;
  #pragma unroll 1
  for (int s = 0; s < nsteps; ++s){
    const half_t* nsrc = psrc + ((s+1 < nsteps) ? SLOTSTRIDE : 0);
    h4v nxt[5];
    #pragma unroll
    for (int T = 0; T < 5; ++T) nxt[T] = *(const h4v*)(nsrc + pofl + T*256);

    // A fragments from h buffer p (b-major rows)
    const half_t* hrd = hbuf + p*NB*168 + m*168;
    h8v ah[5];
    #pragma unroll
    for (int ks = 0; ks < 5; ++ks) ah[ks] = *(const h8v*)(hrd + ks*32 + kg*8);

    f4v acc[5];
    #pragma unroll
    for (int T = 0; T < 5; ++T){
      f4v a = {0.f, 0.f, 0.f, 0.f};
      #pragma unroll
      for (int ks = 0; ks < 5; ++ks)
        a = __builtin_amdgcn_mfma_f32_16x16x32_f16(ah[ks], bhh[T][ks], a, 0, 0, 0);
      acc[T] = a;
    }

    half_t* hwr = hbuf + (p^1)*NB*168 + bc_*168;
    #pragma unroll
    for (int T = 0; T < 5; ++T){
      float v0 = acc[T][0] + (float)curp[T][0];
      float v1 = acc[T][1] + (float)curp[T][1];
      float v2 = acc[T][2] + (float)curp[T][2];
      float v3 = acc[T][3] + (float)curp[T][3];
      // quad 4x4 transpose: lane ends with (i,f,g,o) of its own cell
      XPOSE_PAIR(v0, v1, o1, 0xB1);
      XPOSE_PAIR(v2, v3, o1, 0xB1);
      XPOSE_PAIR(v0, v2, o2, 0x4E);
      XPOSE_PAIR(v1, v3, o2, 0x4E);
      float cn = hsig(v1)*c_reg[T] + hsig(v0)*tanh_(v2);
      float hn = hsig(v3)*tanh_(cn);
      c_reg[T] = cn;
      hm_reg[T] = fmaxf(hm_reg[T], hn);
      hwr[jc[T]] = (half_t)hn;
    }

    #pragma unroll
    for (int T = 0; T < 5; ++T) curp[T] = nxt[T];

    // lgkm-only barrier: h writes drained, global prefetch NOT force-drained
    asm volatile("s_waitcnt lgkmcnt(0)" ::: "memory");
    __builtin_amdgcn_s_barrier();
    __builtin_amdgcn_sched_barrier(0);
    p ^= 1;
    psrc += SLOTSTRIDE;
  }

  if (!last){
    for (int i = tid; i < NB*168; i += 512) stateH[(size_t)blk*NB*168 + i] = hbuf[p*NB*168 + i];
    float* sc = stateC + ((size_t)blk*512 + tid)*10;
    #pragma unroll
    for (int T = 0; T < 5; ++T){ sc[T] = c_reg[T]; sc[5+T] = hm_reg[T]; }
  } else {
    #pragma unroll
    for (int T = 0; T < 5; ++T){
      if (jc[T] < HID) pooled[(size_t)(b0 + bc_)*300 + d*HID + jc[T]] = hm_reg[T];
    }
  }
}

// ---------------- final MLP + softmax ----------------
__global__ __launch_bounds__(256) void fc(const float* __restrict__ pooled,
                                          const float* __restrict__ w1, const float* __restrict__ b1,
                                          const float* __restrict__ w2, const float* __restrict__ b2,
                                          float* __restrict__ out){
  __shared__ float prow[300];
  __shared__ float ps[64][5];
  __shared__ float z[52];
  __shared__ float lg[12];
  int b = blockIdx.x, tid = threadIdx.x;
  for (int i = tid; i < 300; i += 256) prow[i] = pooled[(size_t)b*300 + i];
  __syncthreads();
  int j = tid & 63, seg = tid >> 6;
  float a = 0.f;
  if (j < 50){
    const float* wr = w1 + (size_t)j*300 + seg*75;
    const float* pr = prow + seg*75;
    #pragma unroll 5
    for (int k = 0; k < 75; ++k) a = fmaf(pr[k], wr[k], a);
  }
  ps[j][seg] = a;
  __syncthreads();
  if (tid < 50) z[tid] = fmaxf(ps[tid][0]+ps[tid][1]+ps[tid][2]+ps[tid][3] + b1[tid], 0.f);
  __syncthreads();
  if (tid < 10){
    float a2 = b2[tid];
    for (int k = 0; k < 50; ++k) a2 = fmaf(z[k], w2[tid*50 + k], a2);
    lg[tid] = a2;
  }
  __syncthreads();
  if (tid < 10){
    float mx = lg[0];
    #pragma unroll
    for (int k = 1; k < 10; ++k) mx = fmaxf(mx, lg[k]);
    float ssum = 0.f;
    #pragma unroll
    for (int k = 0; k < 10; ++k) ssum += __expf(lg[k] - mx);
    out[(size_t)b*10 + tid] = __expf(lg[tid] - mx) / ssum;
  }
}

extern "C" void kernel_launch(void* const* d_in, const int* in_sizes, int n_in,
                              void* d_out, int out_size, void* d_ws, size_t ws_size,
                              hipStream_t stream) {
  const float* x      = (const float*)d_in[0];
  const float* conv_w = (const float*)d_in[1];
  const float* conv_b = (const float*)d_in[2];
  const float* w_ih_f = (const float*)d_in[3];
  const float* w_hh_f = (const float*)d_in[4];
  const float* b_ih_f = (const float*)d_in[5];
  const float* b_hh_f = (const float*)d_in[6];
  const float* w_ih_b = (const float*)d_in[7];
  const float* w_hh_b = (const float*)d_in[8];
  const float* b_ih_b = (const float*)d_in[9];
  const float* b_hh_b = (const float*)d_in[10];
  const float* l1w = (const float*)d_in[11];
  const float* l1b = (const float*)d_in[12];
  const float* l2w = (const float*)d_in[13];
  const float* l2b = (const float*)d_in[14];
  float* out = (float*)d_out;

  char* ws = (char*)d_ws;
  size_t off = 0;
  auto alloc = [&](size_t bytes){ size_t o = off; off += (bytes + 255) & ~(size_t)255; return o; };
  size_t xseq_o = alloc((size_t)BATCH*TSEQ*CH*2);
  size_t pre_o  = alloc((size_t)2*HALF_A*16*10240*2);
  size_t wih_o  = alloc((size_t)2*NPAD*CH*2);
  size_t whh_o  = alloc((size_t)2*NPAD*KPAD*2);
  size_t bs_o   = alloc((size_t)2*NPAD*4);
  size_t pool_o = alloc((size_t)BATCH*300*4);
  size_t stc_o  = alloc((size_t)32*512*10*4);
  size_t sth_o  = alloc((size_t)32*NB*168*2);
  if (off > ws_size){
    fprintf(stderr, "[cnnblstm] WS TOO SMALL: need %zu have %zu\n", off, ws_size);
    return;
  }
  half_t* xseq_p = (half_t*)(ws + xseq_o);
  half_t* pre_p  = (half_t*)(ws + pre_o);
  half_t* wih_p  = (half_t*)(ws + wih_o);
  half_t* whh_p  = (half_t*)(ws + whh_o);
  float*  bs_p   = (float*)(ws + bs_o);
  float*  pool_p = (float*)(ws + pool_o);
  float*  stc_p  = (float*)(ws + stc_o);
  half_t* sth_p  = (half_t*)(ws + sth_o);

  prep_wih <<<(2*NPAD*CH + 255)/256, 256, 0, stream>>>(w_ih_f, w_ih_b, wih_p);
  prep_whh <<<(2*NPAD*KPAD + 255)/256, 256, 0, stream>>>(w_hh_f, w_hh_b, whh_p);
  prep_bsum<<<(2*NPAD + 255)/256, 256, 0, stream>>>(b_ih_f, b_hh_f, b_ih_b, b_hh_b, bs_p);
  conv_pool<<<dim3(BATCH, (TSEQ + CTT - 1)/CTT), 256, 0, stream>>>(x, conv_w, conv_b, xseq_p);

  proj <<<dim3(4, HALF_A, 2), 512, 0, stream>>>(xseq_p, wih_p, bs_p, pre_p, 0);
  recur<<<dim3(16, 2), 512, 0, stream>>>(pre_p, whh_p, pool_p, stc_p, sth_p, 1, 0, HALF_A);
  proj <<<dim3(4, HALF_B, 2), 512, 0, stream>>>(xseq_p, wih_p, bs_p, pre_p, HALF_A);
  recur<<<dim3(16, 2), 512, 0, stream>>>(pre_p, whh_p, pool_p, stc_p, sth_p, 0, 1, HALF_B);

  fc<<<BATCH, 256, 0, stream>>>(pool_p, l1w, l1b, l2w, l2b, out);
}